// Round 6
// baseline (183.892 us; speedup 1.0000x reference)
//
#include <hip/hip_runtime.h>
#include <hip/hip_bf16.h>

// Problem constants
#define B_SZ 256
#define SDIM 1024
#define ADIM 512

#define BK 32
#define NSTEPS (SDIM / BK)   // 32
#define NBUF 4               // LDS buffers (depth-3 prefetch in flight)

typedef __attribute__((ext_vector_type(8))) short bf16x8;
typedef __attribute__((ext_vector_type(4))) float f32x4;

__device__ __forceinline__ unsigned short f2bf(float x) {
  union { float f; unsigned u; } v; v.f = x;
  unsigned r = v.u + 0x7FFFu + ((v.u >> 16) & 1u);   // round-to-nearest-even
  return (unsigned short)(r >> 16);
}

__device__ __forceinline__ void gll16(const void* g, void* l) {
  __builtin_amdgcn_global_load_lds(
      (const __attribute__((address_space(1))) unsigned int*)g,
      (__attribute__((address_space(3))) unsigned int*)l, 16, 0, 0);
}

__device__ __forceinline__ unsigned cvtpk(float lo, float hi) {
  unsigned r;
  asm("v_cvt_pk_bf16_f32 %0, %1, %2" : "=v"(r) : "v"(lo), "v"(hi));
  return r;
}

// ---------------- Kernel 1: small MLPs + obs->bf16 + cw2b dot ----------------
__global__ __launch_bounds__(128) void kprep(
    const float* __restrict__ obs,
    const float* __restrict__ task, const int* __restrict__ action,
    const float* __restrict__ we1, const float* __restrict__ be1,
    const float* __restrict__ we2, const float* __restrict__ be2,
    const float* __restrict__ aw1, const float* __restrict__ aw1b,
    const float* __restrict__ ab1, const float* __restrict__ ab1b,
    const float* __restrict__ ab2, const float* __restrict__ ab2b,
    const float* __restrict__ cw1, const float* __restrict__ cw1b,
    const float* __restrict__ cb1, const float* __restrict__ cb1b,
    const float* __restrict__ cb2, const float* __restrict__ cb2b,
    const float* __restrict__ cw2b,
    float* __restrict__ ws_ha, float* __restrict__ ws_hc,
    unsigned short* __restrict__ ws_obs,
    float* __restrict__ out)
{
  const int b = blockIdx.x, t = threadIdx.x;
  __shared__ float s_task[64], s_t1[64], s_z[64], s_hb[128], s_red[128];

  // obs row b -> bf16 into ws_obs; also dot(cw2b, obs[b])
  float dotc = 0.0f;
  {
    const float4* orow = (const float4*)(obs + (size_t)b * SDIM);
    const float4* crow = (const float4*)cw2b;
    ushort4* wrow = (ushort4*)(ws_obs + (size_t)b * SDIM);
#pragma unroll
    for (int i = 0; i < 2; ++i) {
      const int idx = t + i * 128;
      float4 v = orow[idx];
      float4 w = crow[idx];
      dotc += v.x * w.x + v.y * w.y + v.z * w.z + v.w * w.w;
      ushort4 u;
      u.x = f2bf(v.x); u.y = f2bf(v.y); u.z = f2bf(v.z); u.w = f2bf(v.w);
      wrow[idx] = u;
    }
  }

  if (t < 64) s_task[t] = task[b * 64 + t];
  __syncthreads();
  if (t < 64) {
    float a = be1[t];
    for (int e = 0; e < 64; ++e) a += s_task[e] * we1[e * 64 + t];
    s_t1[t] = fmaxf(a, 0.0f);
  }
  __syncthreads();
  if (t < 64) {
    float a = be2[t];
    for (int e = 0; e < 64; ++e) a += s_t1[e] * we2[e * 64 + t];
    s_z[t] = fmaxf(a, 0.0f);
  }
  __syncthreads();
  {
    float a1 = aw1b[t], a2 = ab1b[t], a3 = cw1b[t], a4 = cb1b[t];
    for (int e = 0; e < 64; ++e) {
      const float zv = s_z[e];
      a1 += zv * aw1[e * 128 + t];
      a2 += zv * ab1[e * 128 + t];
      a3 += zv * cw1[e * 128 + t];
      a4 += zv * cb1[e * 128 + t];
    }
    ws_ha[b * 128 + t] = fmaxf(a1, 0.0f);
    s_hb[t] = fmaxf(a2, 0.0f);
    ws_hc[b * 128 + t] = fmaxf(a3, 0.0f);
    s_red[t] = fmaxf(a4, 0.0f) * cb2[t] + dotc;   // bv partial + cw2b.obs partial
  }
  __syncthreads();
  // ba -> staged into d_out logits slots (khyper atomically accumulates on top)
  for (int o = t; o < ADIM; o += 128) {
    float a = ab2b[o];
    for (int h = 0; h < 128; ++h) a += s_hb[h] * ab2[h * ADIM + o];
    out[b * ADIM + o] = a;
  }
  // bv + cw2b.obs reduction
  for (int s = 64; s > 0; s >>= 1) {
    __syncthreads();
    if (t < s) s_red[t] += s_red[t + s];
  }
  if (t == 0) {
    out[131840 + b] = s_red[0] + cb2b[0];      // v partial; critic block adds rest
    out[131072 + b] = (float)action[b];        // action as float
  }
}

// ---------------- Kernel 2: hypernet GEMM, m97-style global_load_lds pipeline --------
// One o per block. W staged f32 -> LDS via global_load_lds (zero regs, fire-and-forget),
// 4-buffer deep, counted vmcnt (never 0 mid-loop). bf16 conversion at ds_read (cvt_pk).
// Source-address XOR swizzle (LDS stays linear per global_load_lds constraint).
__global__ __launch_bounds__(512, 1) void khyper(
    const unsigned short* __restrict__ ws_obs,
    const float* __restrict__ aw2, const float* __restrict__ aw2b,
    const float* __restrict__ cw2,
    const float* __restrict__ ws_ha, const float* __restrict__ ws_hc,
    float* __restrict__ d_out)
{
  __shared__ float Wl[NBUF][128 * BK];           // 4 x 16 KB f32
  __shared__ unsigned short Al[NBUF][256 * BK];  // 4 x 16 KB bf16

  const int tid = threadIdx.x;
  const int blk = blockIdx.x;

  // Block roles: 0..511 actor o-col; 512..515 bias (aw2b, 128 o-cols each); 516 critic
  int wtype;
  int o0 = 0;
  const float* Wbase;
  size_t wstride;
  if (blk < 512)      { wtype = 0; o0 = blk; Wbase = aw2 + (size_t)blk * SDIM; wstride = (size_t)ADIM * SDIM; }
  else if (blk < 516) { wtype = 1; o0 = (blk - 512) * 128; Wbase = aw2b + (size_t)o0 * SDIM; wstride = SDIM; }
  else                { wtype = 2; Wbase = cw2; wstride = SDIM; }

  const int wv = tid >> 6;
  const int lane = tid & 63;

  // ---- staging precompute (source pre-swizzled, LDS linear) ----
  // W: 1024 slots = [128 rows n][8 chunks cs of 16B]; slot stores global k-chunk cs^(n&7)
  // A: 1024 slots = [256 rows b][4 chunks ca of 16B]; slot stores global k-chunk ca^(b&3)
  const float* wsrc[2];
  const unsigned short* asrc[2];
#pragma unroll
  for (int p = 0; p < 2; ++p) {
    const int sw = p * 512 + tid;
    const int n = sw >> 3, cs = sw & 7;
    wsrc[p] = Wbase + (size_t)n * wstride + ((cs ^ (n & 7)) << 2);
    const int b = sw >> 2, ca = sw & 3;
    asrc[p] = ws_obs + (size_t)b * SDIM + ((ca ^ (b & 3)) << 3);
  }

  auto STAGE = [&](int t) {
    const int buf = t & (NBUF - 1);
    const int k0 = t * BK;                       // elements
    char* wb = (char*)(&Wl[buf][0]) + wv * 1024; // wave-uniform; HW adds lane*16
    char* ab = (char*)(&Al[buf][0]) + wv * 1024;
    gll16(wsrc[0] + k0, wb);
    gll16(wsrc[1] + k0, wb + 8192);
    gll16(asrc[0] + k0, ab);
    gll16(asrc[1] + k0, ab + 8192);
  };

  // ---- fragment read offsets ----
  const int mbase = (wv & 3) * 64;     // 4 M-groups over b=256
  const int nbaseL = (wv >> 2) * 64;   // 2 N-groups over n=128
  const int lrow = lane & 15;
  const int grp = lane >> 4;

  int aoff[4];
#pragma unroll
  for (int mf = 0; mf < 4; ++mf) {
    const int b = mbase + mf * 16 + lrow;
    aoff[mf] = b * 64 + ((grp ^ (lrow & 3)) << 4);          // bytes in A buf
  }
  int woff[4][2];
#pragma unroll
  for (int nf = 0; nf < 4; ++nf) {
    const int n = nbaseL + nf * 16 + lrow;
    woff[nf][0] = n * 128 + (((2 * grp) ^ (lrow & 7)) << 4);      // bytes in W buf
    woff[nf][1] = n * 128 + (((2 * grp + 1) ^ (lrow & 7)) << 4);
  }

  f32x4 acc[4][4];
#pragma unroll
  for (int mf = 0; mf < 4; ++mf)
#pragma unroll
    for (int nf = 0; nf < 4; ++nf) acc[mf][nf] = (f32x4)(0.0f);

  auto COMPUTE = [&](int t) {
    const int buf = t & (NBUF - 1);
    const char* ab = (const char*)(&Al[buf][0]);
    const char* wb = (const char*)(&Wl[buf][0]);
    bf16x8 af[4];
#pragma unroll
    for (int mf = 0; mf < 4; ++mf)
      af[mf] = *(const bf16x8*)(ab + aoff[mf]);
    bf16x8 bfr[4];
#pragma unroll
    for (int nf = 0; nf < 4; ++nf) {
      float4 x = *(const float4*)(wb + woff[nf][0]);
      float4 y = *(const float4*)(wb + woff[nf][1]);
      union { bf16x8 v; unsigned u[4]; } q;
      q.u[0] = cvtpk(x.x, x.y);
      q.u[1] = cvtpk(x.z, x.w);
      q.u[2] = cvtpk(y.x, y.y);
      q.u[3] = cvtpk(y.z, y.w);
      bfr[nf] = q.v;
    }
#pragma unroll
    for (int mf = 0; mf < 4; ++mf)
#pragma unroll
      for (int nf = 0; nf < 4; ++nf)
        acc[mf][nf] = __builtin_amdgcn_mfma_f32_16x16x32_bf16(af[mf], bfr[nf], acc[mf][nf], 0, 0, 0);
  };

  // ---- pipeline: counted vmcnt, one barrier pair per K-step ----
  STAGE(0); STAGE(1); STAGE(2); STAGE(3);
#pragma unroll 1
  for (int t = 0; t < NSTEPS; ++t) {
    if (t <= NSTEPS - 4)      asm volatile("s_waitcnt vmcnt(12)" ::: "memory");
    else if (t == NSTEPS - 3) asm volatile("s_waitcnt vmcnt(8)" ::: "memory");
    else if (t == NSTEPS - 2) asm volatile("s_waitcnt vmcnt(4)" ::: "memory");
    else                      asm volatile("s_waitcnt vmcnt(0)" ::: "memory");
    __builtin_amdgcn_s_barrier();
    __builtin_amdgcn_sched_barrier(0);
    COMPUTE(t);
    asm volatile("s_waitcnt lgkmcnt(0)" ::: "memory");
    __builtin_amdgcn_sched_barrier(0);
    __builtin_amdgcn_s_barrier();
    if (t + 4 < NSTEPS) STAGE(t + 4);
  }

  // ---- epilogue ----
  // D element (reg r, lane): b = mbase+mf*16+grp*4+r ; n = nbaseL+nf*16+lrow  (r1-verified)
  if (wtype == 1) {
    // bias: logits[b, o0+n] += G[b,n]
#pragma unroll
    for (int mf = 0; mf < 4; ++mf) {
      const int b = mbase + mf * 16 + grp * 4;
#pragma unroll
      for (int nf = 0; nf < 4; ++nf) {
        const int col = o0 + nbaseL + nf * 16 + lrow;
#pragma unroll
        for (int r = 0; r < 4; ++r)
          atomicAdd(&d_out[(size_t)(b + r) * ADIM + col], acc[mf][nf][r]);
      }
    }
  } else {
    const float* haW = (wtype == 0) ? ws_ha : ws_hc;
    float val[4][4];
#pragma unroll
    for (int mf = 0; mf < 4; ++mf)
#pragma unroll
      for (int r = 0; r < 4; ++r) val[mf][r] = 0.0f;
#pragma unroll
    for (int nf = 0; nf < 4; ++nf) {
      const int hidx = nbaseL + nf * 16 + lrow;
#pragma unroll
      for (int mf = 0; mf < 4; ++mf) {
        const int b = mbase + mf * 16 + grp * 4;
#pragma unroll
        for (int r = 0; r < 4; ++r)
          val[mf][r] += haW[(size_t)(b + r) * 128 + hidx] * acc[mf][nf][r];
      }
    }
#pragma unroll
    for (int mf = 0; mf < 4; ++mf)
#pragma unroll
      for (int r = 0; r < 4; ++r) {
        float v = val[mf][r];
        v += __shfl_xor(v, 1, 64);
        v += __shfl_xor(v, 2, 64);
        v += __shfl_xor(v, 4, 64);
        v += __shfl_xor(v, 8, 64);
        val[mf][r] = v;
      }
    if (lrow == 0) {
#pragma unroll
      for (int mf = 0; mf < 4; ++mf) {
        const int b = mbase + mf * 16 + grp * 4;
#pragma unroll
        for (int r = 0; r < 4; ++r) {
          if (wtype == 0) atomicAdd(&d_out[(size_t)(b + r) * ADIM + o0], val[mf][r]);
          else            atomicAdd(&d_out[131840 + b + r], val[mf][r]);
        }
      }
    }
  }
}

// ---------------- Kernel 3: log_softmax / entropy / log_prob ----------------
__global__ __launch_bounds__(256) void kfinal(const int* __restrict__ action,
                                              float* __restrict__ d_out)
{
  const int b = blockIdx.x, t = threadIdx.x;
  const float* lrow = d_out + (size_t)b * ADIM;
  __shared__ float sM[4], sS[4], sT[4];

  const float x0 = lrow[t], x1 = lrow[t + 256];
  float m = fmaxf(x0, x1);
#pragma unroll
  for (int s = 1; s < 64; s <<= 1) m = fmaxf(m, __shfl_xor(m, s, 64));
  const int wv = t >> 6, ln = t & 63;
  if (ln == 0) sM[wv] = m;
  __syncthreads();
  m = fmaxf(fmaxf(sM[0], sM[1]), fmaxf(sM[2], sM[3]));

  const float d0 = x0 - m, d1 = x1 - m;
  const float e0 = expf(d0), e1 = expf(d1);
  float s1 = e0 + e1;
  float s2 = e0 * d0 + e1 * d1;
#pragma unroll
  for (int s = 1; s < 64; s <<= 1) {
    s1 += __shfl_xor(s1, s, 64);
    s2 += __shfl_xor(s2, s, 64);
  }
  if (ln == 0) { sS[wv] = s1; sT[wv] = s2; }
  __syncthreads();
  if (t == 0) {
    const float S = sS[0] + sS[1] + sS[2] + sS[3];
    const float T = sT[0] + sT[1] + sT[2] + sT[3];
    const float lnS = logf(S);
    const int a = action[b];
    d_out[131328 + b] = (lrow[a] - m) - lnS;   // log_prob
    d_out[131584 + b] = lnS - T / S;           // entropy
  }
}

extern "C" void kernel_launch(void* const* d_in, const int* in_sizes, int n_in,
                              void* d_out_v, int out_size, void* d_ws, size_t ws_size,
                              hipStream_t stream) {
  const float* obs   = (const float*)d_in[0];
  const float* task  = (const float*)d_in[1];
  const int*   action= (const int*)  d_in[2];
  const float* we1   = (const float*)d_in[3];
  const float* be1   = (const float*)d_in[4];
  const float* we2   = (const float*)d_in[5];
  const float* be2   = (const float*)d_in[6];
  const float* aw1   = (const float*)d_in[7];
  const float* aw1b  = (const float*)d_in[8];
  const float* aw2   = (const float*)d_in[9];
  const float* aw2b  = (const float*)d_in[10];
  const float* ab1   = (const float*)d_in[11];
  const float* ab1b  = (const float*)d_in[12];
  const float* ab2   = (const float*)d_in[13];
  const float* ab2b  = (const float*)d_in[14];
  const float* cw1   = (const float*)d_in[15];
  const float* cw1b  = (const float*)d_in[16];
  const float* cw2   = (const float*)d_in[17];
  const float* cw2b  = (const float*)d_in[18];
  const float* cb1   = (const float*)d_in[19];
  const float* cb1b  = (const float*)d_in[20];
  const float* cb2   = (const float*)d_in[21];
  const float* cb2b  = (const float*)d_in[22];
  float* out = (float*)d_out_v;
  float* ws_ha = (float*)d_ws;                       // [256][128] f32
  float* ws_hc = ws_ha + 256 * 128;                  // [256][128] f32
  unsigned short* ws_obs = (unsigned short*)(ws_hc + 256 * 128);  // [256][1024] bf16

  kprep<<<256, 128, 0, stream>>>(obs, task, action, we1, be1, we2, be2, aw1, aw1b,
                                 ab1, ab1b, ab2, ab2b, cw1, cw1b, cb1, cb1b,
                                 cb2, cb2b, cw2b, ws_ha, ws_hc, ws_obs, out);
  // 512 actor + 4 bias + 1 critic
  khyper<<<517, 512, 0, stream>>>(ws_obs, aw2, aw2b, cw2, ws_ha, ws_hc, out);
  kfinal<<<256, 256, 0, stream>>>(action, out);
}